// Round 1
// baseline (424.056 us; speedup 1.0000x reference)
//
#include <hip/hip_runtime.h>
#include <math.h>

#define NPTS 4096
#define MPTS 4096
#define NSTEPS 8
#define ICP_TOL 1e-6f
#define PTS_PER_BLOCK 16
#define NN_BLOCK 1024

// Workspace layout (floats):
//   state[0..12]  : batch0 { Rcum(9 row-major), tcum(3), err(1) }
//   state[13..25] : batch1 { ... }
//   state[26]     : done flag (0/1)
//   acc = ws+32   : per batch b at b*16: { Sp(3), Sq(3), Spq(9 row-major), sum_d(1) }

__global__ void init_kernel(float* __restrict__ state, float* __restrict__ acc) {
    int t = threadIdx.x;
    if (t < 32) acc[t] = 0.f;
    if (t < 2) {
        float* st = state + t * 13;
        st[0] = 1.f; st[1] = 0.f; st[2] = 0.f;
        st[3] = 0.f; st[4] = 1.f; st[5] = 0.f;
        st[6] = 0.f; st[7] = 0.f; st[8] = 1.f;
        st[9] = 0.f; st[10] = 0.f; st[11] = 0.f;
        st[12] = 0.f;  // err
    }
    if (t == 0) state[26] = 0.f;
}

__global__ __launch_bounds__(NN_BLOCK) void nn_step(
    const float* __restrict__ psrc, const float* __restrict__ ptgt,
    const float* __restrict__ state, float* __restrict__ acc) {
    __shared__ float tx[MPTS], ty[MPTS], tz[MPTS];   // 48 KB
    __shared__ float wred[PTS_PER_BLOCK][8];

    const int blocksPerBatch = NPTS / PTS_PER_BLOCK;  // 256
    int b = blockIdx.x / blocksPerBatch;
    int chunk = blockIdx.x % blocksPerBatch;

    const float* tg = ptgt + (size_t)b * MPTS * 3;
    for (int m = threadIdx.x; m < MPTS; m += NN_BLOCK) {
        tx[m] = tg[3 * m + 0];
        ty[m] = tg[3 * m + 1];
        tz[m] = tg[3 * m + 2];
    }

    const float* st = state + b * 13;
    float R00 = st[0], R01 = st[1], R02 = st[2];
    float R10 = st[3], R11 = st[4], R12 = st[5];
    float R20 = st[6], R21 = st[7], R22 = st[8];
    float t0 = st[9], t1 = st[10], t2 = st[11];
    __syncthreads();

    int wave = threadIdx.x >> 6;
    int lane = threadIdx.x & 63;
    int n = chunk * PTS_PER_BLOCK + wave;

    const float* p = psrc + ((size_t)b * NPTS + n) * 3;
    float p0 = p[0], p1 = p[1], p2 = p[2];
    float px = R00 * p0 + R01 * p1 + R02 * p2 + t0;
    float py = R10 * p0 + R11 * p1 + R12 * p2 + t1;
    float pz = R20 * p0 + R21 * p1 + R22 * p2 + t2;

    float bestd = 3.0e38f;
    int besti = 0;
#pragma unroll 4
    for (int k = 0; k < MPTS / 64; ++k) {
        int m = k * 64 + lane;
        float dx = px - tx[m];
        float dy = py - ty[m];
        float dz = pz - tz[m];
        float d = dx * dx + dy * dy + dz * dz;
        if (d < bestd) { bestd = d; besti = m; }  // strict < keeps smallest m per lane
    }
    // wave-wide min + argmin (first-occurrence = smallest index tie-break)
    for (int off = 32; off > 0; off >>= 1) {
        float od = __shfl_xor(bestd, off);
        int oi = __shfl_xor(besti, off);
        if (od < bestd || (od == bestd && oi < besti)) { bestd = od; besti = oi; }
    }
    if (lane == 0) {
        wred[wave][0] = px;
        wred[wave][1] = py;
        wred[wave][2] = pz;
        wred[wave][3] = tx[besti];
        wred[wave][4] = ty[besti];
        wred[wave][5] = tz[besti];
        wred[wave][6] = sqrtf(fmaxf(bestd, 0.f));
    }
    __syncthreads();
    // 16 component sums over the block's PTS_PER_BLOCK points, one atomic each
    if (threadIdx.x < 16) {
        int j = threadIdx.x;
        float s = 0.f;
        for (int w = 0; w < PTS_PER_BLOCK; ++w) {
            float v;
            if (j < 6) v = wred[w][j];                                  // Sp, Sq
            else if (j < 15) v = wred[w][(j - 6) / 3] * wred[w][3 + (j - 6) % 3];  // Spq
            else v = wred[w][6];                                        // sum_d
            s += v;
        }
        atomicAdd(&acc[b * 16 + j], s);
    }
}

__device__ void jacobi4(float A[4][4], float V[4][4]) {
    for (int i = 0; i < 4; ++i)
        for (int j = 0; j < 4; ++j) V[i][j] = (i == j) ? 1.f : 0.f;
    for (int sweep = 0; sweep < 12; ++sweep) {
        for (int p = 0; p < 3; ++p) {
            for (int q = p + 1; q < 4; ++q) {
                float apq = A[p][q];
                if (fabsf(apq) < 1e-30f) continue;
                float theta = (A[q][q] - A[p][p]) / (2.f * apq);
                float t = 1.f / (fabsf(theta) + sqrtf(theta * theta + 1.f));
                if (theta < 0.f) t = -t;
                float c = 1.f / sqrtf(t * t + 1.f);
                float s = t * c;
                for (int k = 0; k < 4; ++k) {  // A <- A*J
                    float akp = A[k][p], akq = A[k][q];
                    A[k][p] = c * akp - s * akq;
                    A[k][q] = s * akp + c * akq;
                }
                for (int k = 0; k < 4; ++k) {  // A <- J^T*A
                    float apk = A[p][k], aqk = A[q][k];
                    A[p][k] = c * apk - s * aqk;
                    A[q][k] = s * apk + c * aqk;
                }
                for (int k = 0; k < 4; ++k) {  // V <- V*J
                    float vkp = V[k][p], vkq = V[k][q];
                    V[k][p] = c * vkp - s * vkq;
                    V[k][q] = s * vkp + c * vkq;
                }
            }
        }
    }
}

__global__ void kabsch_step(float* __restrict__ state, float* __restrict__ acc,
                            float* __restrict__ out, int last) {
    __shared__ float convs[2];
    int tid = threadIdx.x;
    float done_old = state[26];

    float a[16];
    float err_b = 0.f, errnew = 0.f;
    if (tid < 2) {
        for (int i = 0; i < 16; ++i) a[i] = acc[tid * 16 + i];
        err_b = state[tid * 13 + 12];
        errnew = a[15] * (1.f / NPTS);
        convs[tid] = (fabsf(errnew - err_b) < ICP_TOL) ? 1.f : 0.f;
    }
    __syncthreads();
    bool conv = (convs[0] != 0.f) && (convs[1] != 0.f);
    bool done_new = (done_old != 0.f) || conv;

    if (tid < 2 && !done_new) {
        const float inv_n = 1.f / NPTS;
        float pmx = a[0] * inv_n, pmy = a[1] * inv_n, pmz = a[2] * inv_n;
        float qmx = a[3] * inv_n, qmy = a[4] * inv_n, qmz = a[5] * inv_n;
        // H = Spq - Sp Sq^T / n  (H[i][j] = sum p_i q_j, centered)
        float H[3][3];
        for (int i = 0; i < 3; ++i)
            for (int j = 0; j < 3; ++j)
                H[i][j] = a[6 + 3 * i + j] - a[i] * a[3 + j] * inv_n;

        float Sxx = H[0][0], Sxy = H[0][1], Sxz = H[0][2];
        float Syx = H[1][0], Syy = H[1][1], Syz = H[1][2];
        float Szx = H[2][0], Szy = H[2][1], Szz = H[2][2];

        float A[4][4];
        A[0][0] = Sxx + Syy + Szz;
        A[0][1] = Syz - Szy;
        A[0][2] = Szx - Sxz;
        A[0][3] = Sxy - Syx;
        A[1][1] = Sxx - Syy - Szz;
        A[1][2] = Sxy + Syx;
        A[1][3] = Szx + Sxz;
        A[2][2] = -Sxx + Syy - Szz;
        A[2][3] = Syz + Szy;
        A[3][3] = -Sxx - Syy + Szz;
        A[1][0] = A[0][1]; A[2][0] = A[0][2]; A[3][0] = A[0][3];
        A[2][1] = A[1][2]; A[3][1] = A[1][3]; A[3][2] = A[2][3];

        float V[4][4];
        jacobi4(A, V);
        int bi = 0;
        float bv = A[0][0];
        for (int i = 1; i < 4; ++i)
            if (A[i][i] > bv) { bv = A[i][i]; bi = i; }
        float qw = V[0][bi], qx = V[1][bi], qy = V[2][bi], qz = V[3][bi];
        float nr = 1.f / sqrtf(qw * qw + qx * qx + qy * qy + qz * qz);
        qw *= nr; qx *= nr; qy *= nr; qz *= nr;

        float R00 = 1.f - 2.f * (qy * qy + qz * qz);
        float R01 = 2.f * (qx * qy - qw * qz);
        float R02 = 2.f * (qx * qz + qw * qy);
        float R10 = 2.f * (qx * qy + qw * qz);
        float R11 = 1.f - 2.f * (qx * qx + qz * qz);
        float R12 = 2.f * (qy * qz - qw * qx);
        float R20 = 2.f * (qx * qz - qw * qy);
        float R21 = 2.f * (qy * qz + qw * qx);
        float R22 = 1.f - 2.f * (qx * qx + qy * qy);

        float tx = qmx - (R00 * pmx + R01 * pmy + R02 * pmz);
        float ty = qmy - (R10 * pmx + R11 * pmy + R12 * pmz);
        float tz = qmz - (R20 * pmx + R21 * pmy + R22 * pmz);

        // compose: Rcum' = R * Rcum ; tcum' = R * tcum + t
        float* st = state + tid * 13;
        float C00 = st[0], C01 = st[1], C02 = st[2];
        float C10 = st[3], C11 = st[4], C12 = st[5];
        float C20 = st[6], C21 = st[7], C22 = st[8];
        float T0 = st[9], T1 = st[10], T2 = st[11];

        st[0] = R00 * C00 + R01 * C10 + R02 * C20;
        st[1] = R00 * C01 + R01 * C11 + R02 * C21;
        st[2] = R00 * C02 + R01 * C12 + R02 * C22;
        st[3] = R10 * C00 + R11 * C10 + R12 * C20;
        st[4] = R10 * C01 + R11 * C11 + R12 * C21;
        st[5] = R10 * C02 + R11 * C12 + R12 * C22;
        st[6] = R20 * C00 + R21 * C10 + R22 * C20;
        st[7] = R20 * C01 + R21 * C11 + R22 * C21;
        st[8] = R20 * C02 + R21 * C12 + R22 * C22;
        st[9]  = R00 * T0 + R01 * T1 + R02 * T2 + tx;
        st[10] = R10 * T0 + R11 * T1 + R12 * T2 + ty;
        st[11] = R20 * T0 + R21 * T1 + R22 * T2 + tz;
        st[12] = errnew;
    }
    __syncthreads();
    if (tid == 0) state[26] = done_new ? 1.f : 0.f;
    if (tid < 32) acc[tid] = 0.f;  // ready for next step (after sync; reads done)

    if (last && tid < 2) {
        float* st = state + tid * 13;
        float r00 = st[0], r01 = st[1], r02 = st[2];
        float r10 = st[3], r11 = st[4], r12 = st[5];
        float r20 = st[6], r21 = st[7], r22 = st[8];
        float qw = 0.5f * sqrtf(fmaxf(1.f + r00 + r11 + r22, 1e-12f));
        float qx = 0.5f * sqrtf(fmaxf(1.f + r00 - r11 - r22, 1e-12f));
        float qy = 0.5f * sqrtf(fmaxf(1.f - r00 + r11 - r22, 1e-12f));
        float qz = 0.5f * sqrtf(fmaxf(1.f - r00 - r11 + r22, 1e-12f));
        qx = (r21 - r12 >= 0.f) ? qx : -qx;
        qy = (r02 - r20 >= 0.f) ? qy : -qy;
        qz = (r10 - r01 >= 0.f) ? qz : -qz;
        out[tid * 7 + 0] = st[9];
        out[tid * 7 + 1] = st[10];
        out[tid * 7 + 2] = st[11];
        out[tid * 7 + 3] = qx;
        out[tid * 7 + 4] = qy;
        out[tid * 7 + 5] = qz;
        out[tid * 7 + 6] = qw;
    }
}

extern "C" void kernel_launch(void* const* d_in, const int* in_sizes, int n_in,
                              void* d_out, int out_size, void* d_ws, size_t ws_size,
                              hipStream_t stream) {
    const float* psrc = (const float*)d_in[0];
    const float* ptgt = (const float*)d_in[1];
    float* out = (float*)d_out;
    float* ws = (float*)d_ws;
    float* state = ws;        // 27 floats (padded to 32)
    float* acc = ws + 32;     // 32 floats

    init_kernel<<<1, 64, 0, stream>>>(state, acc);
    const int nblocks = 2 * (NPTS / PTS_PER_BLOCK);  // 512
    for (int s = 0; s < NSTEPS; ++s) {
        nn_step<<<dim3(nblocks), dim3(NN_BLOCK), 0, stream>>>(psrc, ptgt, state, acc);
        kabsch_step<<<1, 64, 0, stream>>>(state, acc, out, (s == NSTEPS - 1) ? 1 : 0);
    }
}

// Round 2
// 298.225 us; speedup vs baseline: 1.4219x; 1.4219x over previous
//
#include <hip/hip_runtime.h>
#include <math.h>

#define NPTS 4096
#define MPTS 4096
#define NSTEPS 8
#define ICP_TOL 1e-6f

// Workspace layout (floats):
//   state[0..12]  : batch0 { Rcum(9 row-major), tcum(3), err(1) }
//   state[13..25] : batch1 { ... }
//   state[26]     : done flag (0/1)
//   acc  = ws+32  : per batch b at b*16: { Sp(3), Sq(3), Spq(9 row-major), sum_d(1) }
//   ptgt4 = ws+64 : interleaved targets [b][m] = {x, y, z, 0.5*|t|^2}  (2*4096*4 floats)

__global__ void init_kernel(const float* __restrict__ ptgt,
                            float* __restrict__ state, float* __restrict__ acc,
                            float* __restrict__ ptgt4) {
    int gid = blockIdx.x * 256 + threadIdx.x;
    if (gid < 2 * MPTS) {
        float x = ptgt[3 * gid + 0];
        float y = ptgt[3 * gid + 1];
        float z = ptgt[3 * gid + 2];
        float4 v;
        v.x = x; v.y = y; v.z = z;
        v.w = 0.5f * (x * x + y * y + z * z);
        ((float4*)ptgt4)[gid] = v;
    }
    if (blockIdx.x == 0) {
        int t = threadIdx.x;
        if (t < 32) acc[t] = 0.f;
        if (t < 2) {
            float* st = state + t * 13;
            st[0] = 1.f; st[1] = 0.f; st[2] = 0.f;
            st[3] = 0.f; st[4] = 1.f; st[5] = 0.f;
            st[6] = 0.f; st[7] = 0.f; st[8] = 1.f;
            st[9] = 0.f; st[10] = 0.f; st[11] = 0.f;
            st[12] = 0.f;  // err
        }
        if (t == 0) state[26] = 0.f;
    }
}

// 512 blocks x 256 threads. Block handles 16 source points (all 4 waves share
// them); wave w scans target slice [w*1024, (w+1)*1024). Each lane streams one
// float4 target per iter from L2 (coalesced); 16 points amortize each load.
// Per (point,target) pair: s = p.t - |t|^2/2  (argmax s == argmin dist), 6 VALU.
__global__ __launch_bounds__(256) void nn_step(
    const float* __restrict__ psrc, const float* __restrict__ ptgt4,
    const float* __restrict__ state, float* __restrict__ acc) {
    __shared__ unsigned keys[4][16];
    __shared__ float red[16][16];

    const int blocksPerBatch = NPTS / 16;  // 256
    int b = blockIdx.x / blocksPerBatch;
    int n0 = (blockIdx.x % blocksPerBatch) * 16;

    const float* st = state + b * 13;
    float R00 = st[0], R01 = st[1], R02 = st[2];
    float R10 = st[3], R11 = st[4], R12 = st[5];
    float R20 = st[6], R21 = st[7], R22 = st[8];
    float t0 = st[9], t1 = st[10], t2 = st[11];

    // transformed source points (wave-uniform values, held per-lane)
    float pxv[16], pyv[16], pzv[16];
    const float* ps = psrc + ((size_t)b * NPTS + n0) * 3;
#pragma unroll
    for (int i = 0; i < 16; ++i) {
        float x = ps[3 * i + 0], y = ps[3 * i + 1], z = ps[3 * i + 2];
        pxv[i] = fmaf(R00, x, fmaf(R01, y, fmaf(R02, z, t0)));
        pyv[i] = fmaf(R10, x, fmaf(R11, y, fmaf(R12, z, t1)));
        pzv[i] = fmaf(R20, x, fmaf(R21, y, fmaf(R22, z, t2)));
    }

    int tid = threadIdx.x;
    int w = tid >> 6, lane = tid & 63;
    int m0 = w * 1024 + lane;
    const float4* tp = (const float4*)ptgt4 + ((size_t)b * MPTS + m0);

    float best[16];
    int idx[16];
#pragma unroll
    for (int i = 0; i < 16; ++i) { best[i] = -3.0e38f; idx[i] = m0; }

    float4 tc = tp[0];
    int mreg = m0;
#pragma unroll
    for (int k = 0; k < 16; ++k) {
        float4 tnx = tp[((k + 1) & 15) * 64];  // prefetch (wraps harmlessly)
        float tx = tc.x, ty = tc.y, tz = tc.z, htn = tc.w;
#pragma unroll
        for (int i = 0; i < 16; ++i) {
            float s = fmaf(pxv[i], tx, fmaf(pyv[i], ty, fmaf(pzv[i], tz, -htn)));
            if (s > best[i]) { best[i] = s; idx[i] = mreg; }
        }
        mreg += 64;
        tc = tnx;
    }

    // wave argmax via order-preserving packed key: score hi-20 bits | (4095-m).
    // max key -> max score, ties -> min index (12 low score bits collapsed:
    // only near-degenerate ties can differ from reference; negligible in H).
#pragma unroll
    for (int i = 0; i < 16; ++i) {
        unsigned ub = __float_as_uint(best[i]);
        unsigned u = (__float_as_int(best[i]) >= 0) ? (ub | 0x80000000u) : ~ub;
        unsigned key = (u & 0xFFFFF000u) | (4095u - (unsigned)idx[i]);
        for (int off = 32; off; off >>= 1) {
            unsigned o = (unsigned)__shfl_xor((int)key, off);
            key = key > o ? key : o;
        }
        if (lane == 0) keys[w][i] = key;
    }
    __syncthreads();

    if (tid < 16) {
        unsigned key = keys[0][tid];
        unsigned k1 = keys[1][tid], k2 = keys[2][tid], k3 = keys[3][tid];
        key = key > k1 ? key : k1;
        key = key > k2 ? key : k2;
        key = key > k3 ? key : k3;
        int m = 4095 - (int)(key & 0xFFFu);
        float4 q = ((const float4*)ptgt4)[(size_t)b * MPTS + m];
        const float* pp = psrc + ((size_t)b * NPTS + n0 + tid) * 3;
        float x = pp[0], y = pp[1], z = pp[2];
        float px = fmaf(R00, x, fmaf(R01, y, fmaf(R02, z, t0)));
        float py = fmaf(R10, x, fmaf(R11, y, fmaf(R12, z, t1)));
        float pz = fmaf(R20, x, fmaf(R21, y, fmaf(R22, z, t2)));
        float dx = px - q.x, dy = py - q.y, dz = pz - q.z;
        float dist = sqrtf(dx * dx + dy * dy + dz * dz);
        red[tid][0] = px; red[tid][1] = py; red[tid][2] = pz;
        red[tid][3] = q.x; red[tid][4] = q.y; red[tid][5] = q.z;
        red[tid][6] = px * q.x;  red[tid][7] = px * q.y;  red[tid][8] = px * q.z;
        red[tid][9] = py * q.x;  red[tid][10] = py * q.y; red[tid][11] = py * q.z;
        red[tid][12] = pz * q.x; red[tid][13] = pz * q.y; red[tid][14] = pz * q.z;
        red[tid][15] = dist;
    }
    __syncthreads();
    if (tid < 16) {
        float s = 0.f;
#pragma unroll
        for (int r = 0; r < 16; ++r) s += red[r][tid];
        atomicAdd(&acc[b * 16 + tid], s);
    }
}

__device__ void jacobi4(float A[4][4], float V[4][4]) {
    for (int i = 0; i < 4; ++i)
        for (int j = 0; j < 4; ++j) V[i][j] = (i == j) ? 1.f : 0.f;
    for (int sweep = 0; sweep < 6; ++sweep) {
        for (int p = 0; p < 3; ++p) {
            for (int q = p + 1; q < 4; ++q) {
                float apq = A[p][q];
                if (fabsf(apq) < 1e-30f) continue;
                float theta = (A[q][q] - A[p][p]) / (2.f * apq);
                float t = 1.f / (fabsf(theta) + sqrtf(theta * theta + 1.f));
                if (theta < 0.f) t = -t;
                float c = 1.f / sqrtf(t * t + 1.f);
                float s = t * c;
                for (int k = 0; k < 4; ++k) {
                    float akp = A[k][p], akq = A[k][q];
                    A[k][p] = c * akp - s * akq;
                    A[k][q] = s * akp + c * akq;
                }
                for (int k = 0; k < 4; ++k) {
                    float apk = A[p][k], aqk = A[q][k];
                    A[p][k] = c * apk - s * aqk;
                    A[q][k] = s * apk + c * aqk;
                }
                for (int k = 0; k < 4; ++k) {
                    float vkp = V[k][p], vkq = V[k][q];
                    V[k][p] = c * vkp - s * vkq;
                    V[k][q] = s * vkp + c * vkq;
                }
            }
        }
    }
}

__global__ void kabsch_step(float* __restrict__ state, float* __restrict__ acc,
                            float* __restrict__ out, int last) {
    __shared__ float convs[2];
    int tid = threadIdx.x;
    float done_old = state[26];

    float a[16];
    float err_b = 0.f, errnew = 0.f;
    if (tid < 2) {
        for (int i = 0; i < 16; ++i) a[i] = acc[tid * 16 + i];
        err_b = state[tid * 13 + 12];
        errnew = a[15] * (1.f / NPTS);
        convs[tid] = (fabsf(errnew - err_b) < ICP_TOL) ? 1.f : 0.f;
    }
    __syncthreads();
    bool conv = (convs[0] != 0.f) && (convs[1] != 0.f);
    bool done_new = (done_old != 0.f) || conv;

    if (tid < 2 && !done_new) {
        const float inv_n = 1.f / NPTS;
        float pmx = a[0] * inv_n, pmy = a[1] * inv_n, pmz = a[2] * inv_n;
        float qmx = a[3] * inv_n, qmy = a[4] * inv_n, qmz = a[5] * inv_n;
        float H[3][3];
        for (int i = 0; i < 3; ++i)
            for (int j = 0; j < 3; ++j)
                H[i][j] = a[6 + 3 * i + j] - a[i] * a[3 + j] * inv_n;

        float Sxx = H[0][0], Sxy = H[0][1], Sxz = H[0][2];
        float Syx = H[1][0], Syy = H[1][1], Syz = H[1][2];
        float Szx = H[2][0], Szy = H[2][1], Szz = H[2][2];

        float A[4][4];
        A[0][0] = Sxx + Syy + Szz;
        A[0][1] = Syz - Szy;
        A[0][2] = Szx - Sxz;
        A[0][3] = Sxy - Syx;
        A[1][1] = Sxx - Syy - Szz;
        A[1][2] = Sxy + Syx;
        A[1][3] = Szx + Sxz;
        A[2][2] = -Sxx + Syy - Szz;
        A[2][3] = Syz + Szy;
        A[3][3] = -Sxx - Syy + Szz;
        A[1][0] = A[0][1]; A[2][0] = A[0][2]; A[3][0] = A[0][3];
        A[2][1] = A[1][2]; A[3][1] = A[1][3]; A[3][2] = A[2][3];

        float V[4][4];
        jacobi4(A, V);
        int bi = 0;
        float bv = A[0][0];
        for (int i = 1; i < 4; ++i)
            if (A[i][i] > bv) { bv = A[i][i]; bi = i; }
        float qw = V[0][bi], qx = V[1][bi], qy = V[2][bi], qz = V[3][bi];
        float nr = 1.f / sqrtf(qw * qw + qx * qx + qy * qy + qz * qz);
        qw *= nr; qx *= nr; qy *= nr; qz *= nr;

        float R00 = 1.f - 2.f * (qy * qy + qz * qz);
        float R01 = 2.f * (qx * qy - qw * qz);
        float R02 = 2.f * (qx * qz + qw * qy);
        float R10 = 2.f * (qx * qy + qw * qz);
        float R11 = 1.f - 2.f * (qx * qx + qz * qz);
        float R12 = 2.f * (qy * qz - qw * qx);
        float R20 = 2.f * (qx * qz - qw * qy);
        float R21 = 2.f * (qy * qz + qw * qx);
        float R22 = 1.f - 2.f * (qx * qx + qy * qy);

        float tx = qmx - (R00 * pmx + R01 * pmy + R02 * pmz);
        float ty = qmy - (R10 * pmx + R11 * pmy + R12 * pmz);
        float tz = qmz - (R20 * pmx + R21 * pmy + R22 * pmz);

        float* stp = state + tid * 13;
        float C00 = stp[0], C01 = stp[1], C02 = stp[2];
        float C10 = stp[3], C11 = stp[4], C12 = stp[5];
        float C20 = stp[6], C21 = stp[7], C22 = stp[8];
        float T0 = stp[9], T1 = stp[10], T2 = stp[11];

        stp[0] = R00 * C00 + R01 * C10 + R02 * C20;
        stp[1] = R00 * C01 + R01 * C11 + R02 * C21;
        stp[2] = R00 * C02 + R01 * C12 + R02 * C22;
        stp[3] = R10 * C00 + R11 * C10 + R12 * C20;
        stp[4] = R10 * C01 + R11 * C11 + R12 * C21;
        stp[5] = R10 * C02 + R11 * C12 + R12 * C22;
        stp[6] = R20 * C00 + R21 * C10 + R22 * C20;
        stp[7] = R20 * C01 + R21 * C11 + R22 * C21;
        stp[8] = R20 * C02 + R21 * C12 + R22 * C22;
        stp[9]  = R00 * T0 + R01 * T1 + R02 * T2 + tx;
        stp[10] = R10 * T0 + R11 * T1 + R12 * T2 + ty;
        stp[11] = R20 * T0 + R21 * T1 + R22 * T2 + tz;
        stp[12] = errnew;
    }
    __syncthreads();
    if (tid == 0) state[26] = done_new ? 1.f : 0.f;
    if (tid < 32) acc[tid] = 0.f;

    if (last && tid < 2) {
        float* stp = state + tid * 13;
        float r00 = stp[0], r01 = stp[1], r02 = stp[2];
        float r10 = stp[3], r11 = stp[4], r12 = stp[5];
        float r20 = stp[6], r21 = stp[7], r22 = stp[8];
        float qw = 0.5f * sqrtf(fmaxf(1.f + r00 + r11 + r22, 1e-12f));
        float qx = 0.5f * sqrtf(fmaxf(1.f + r00 - r11 - r22, 1e-12f));
        float qy = 0.5f * sqrtf(fmaxf(1.f - r00 + r11 - r22, 1e-12f));
        float qz = 0.5f * sqrtf(fmaxf(1.f - r00 - r11 + r22, 1e-12f));
        qx = (r21 - r12 >= 0.f) ? qx : -qx;
        qy = (r02 - r20 >= 0.f) ? qy : -qy;
        qz = (r10 - r01 >= 0.f) ? qz : -qz;
        out[tid * 7 + 0] = stp[9];
        out[tid * 7 + 1] = stp[10];
        out[tid * 7 + 2] = stp[11];
        out[tid * 7 + 3] = qx;
        out[tid * 7 + 4] = qy;
        out[tid * 7 + 5] = qz;
        out[tid * 7 + 6] = qw;
    }
}

extern "C" void kernel_launch(void* const* d_in, const int* in_sizes, int n_in,
                              void* d_out, int out_size, void* d_ws, size_t ws_size,
                              hipStream_t stream) {
    const float* psrc = (const float*)d_in[0];
    const float* ptgt = (const float*)d_in[1];
    float* out = (float*)d_out;
    float* ws = (float*)d_ws;
    float* state = ws;          // 27 floats (padded to 32)
    float* acc = ws + 32;       // 32 floats
    float* ptgt4 = ws + 64;     // 2*4096*4 floats, 16B-aligned

    init_kernel<<<32, 256, 0, stream>>>(ptgt, state, acc, ptgt4);
    for (int s = 0; s < NSTEPS; ++s) {
        nn_step<<<512, 256, 0, stream>>>(psrc, ptgt4, state, acc);
        kabsch_step<<<1, 64, 0, stream>>>(state, acc, out, (s == NSTEPS - 1) ? 1 : 0);
    }
}